// Round 2
// baseline (221.728 us; speedup 1.0000x reference)
//
#include <hip/hip_runtime.h>

#define NCH 30        // channels per cell
#define CHUNK 128     // cells staged per LDS pass (30.7 KB both arrays)
#define CPB 256       // cells per block (2 chunks)
#define TPB 256       // threads per block

__device__ __forceinline__ float iou_f(float x1, float y1, float w1, float h1,
                                       float x2, float y2, float w2, float h2) {
    float l1 = x1 - 0.5f * w1, r1 = x1 + 0.5f * w1;
    float t1 = y1 - 0.5f * h1, b1 = y1 + 0.5f * h1;
    float l2 = x2 - 0.5f * w2, r2 = x2 + 0.5f * w2;
    float t2 = y2 - 0.5f * h2, b2 = y2 + 0.5f * h2;
    float in_h = fminf(b1, b2) - fmaxf(t1, t2);
    float in_w = fminf(r1, r2) - fmaxf(l1, l2);
    float inter = (in_h < 0.f || in_w < 0.f) ? 0.f : in_h * in_w;
    float a1 = (b1 - t1) * (r1 - l1);
    float a2 = (b2 - t2) * (r2 - l2);
    return inter / (a1 + a2 - inter);
}

// LDS budget: 2 * 128 * 30 * 4 = 30720 B + red -> 5 blocks/CU (20 waves/CU).
// __launch_bounds__(256,5): 5 waves/SIMD needs VGPR <= 102 (current 88, no spill).
__global__ __launch_bounds__(TPB, 5) void yolo_loss(const float* __restrict__ pred,
                                                    const float* __restrict__ lab,
                                                    float* __restrict__ out,
                                                    int n_cells) {
    __shared__ float s_p[CHUNK * NCH];
    __shared__ float s_l[CHUNK * NCH];
    __shared__ float red[5][TPB / 64];

    const int tid = threadIdx.x;
    const size_t cell0 = (size_t)blockIdx.x * CPB;
    const size_t total_vec = (size_t)n_cells * NCH / 4;

    float v0 = 0.f, v1 = 0.f, v2 = 0.f, v3 = 0.f, v4 = 0.f;

    for (int chunk = 0; chunk < 2; ++chunk) {
        const size_t cbase = cell0 + (size_t)chunk * CHUNK;
        const size_t vbase = cbase * NCH / 4;            // float4 index of chunk start
        const float4* gp = (const float4*)pred + vbase;
        const float4* gl = (const float4*)lab + vbase;
        float4* sp = (float4*)s_p;
        float4* sl = (float4*)s_l;

        if (chunk) __syncthreads();     // chunk0 readers done before overwrite

        const int nvec = CHUNK * NCH / 4;                // 960 float4 per array
        const size_t avail = (total_vec > vbase) ? (total_vec - vbase) : 0;
        const int nv = (int)((avail < (size_t)nvec) ? avail : (size_t)nvec);
#pragma unroll
        for (int i = 0; i < nvec; i += TPB) {
            int idx = i + tid;
            if (idx < nv) {
                sp[idx] = gp[idx];
                sl[idx] = gl[idx];
            }
        }
        __syncthreads();

        const int local = tid - chunk * CHUNK;
        if (local >= 0 && local < CHUNK && cbase + (size_t)local < (size_t)n_cells) {
            const float* cp = s_p + local * NCH;
            const float* cl = s_l + local * NCH;
            float mask = cl[0];
            float gx = cl[1], gy = cl[2], gw = cl[3], gh = cl[4];

            float i1 = iou_f(cp[1], cp[2], cp[3], cp[4], gx, gy, gw, gh);
            float i2 = iou_f(cp[6], cp[7], cp[8], cp[9], gx, gy, gw, gh);
            bool best = (i1 >= i2);
            float sx = best ? cp[1] : cp[6];
            float sy = best ? cp[2] : cp[7];
            float sw = best ? cp[3] : cp[8];
            float sh = best ? cp[4] : cp[9];
            float imax = best ? i1 : i2;
            float imin = best ? i2 : i1;

            float center = 5.f * ((sx - gx) * (sx - gx) + (sy - gy) * (sy - gy));
            float dw = sqrtf(sw) - sqrtf(gw);
            float dh = sqrtf(sh) - sqrtf(gh);
            float wh = 5.f * (dw * dw + dh * dh);

            float cls = 0.f;
#pragma unroll
            for (int c = 10; c < 30; ++c) {
                float d = cp[c] - cl[c];
                cls += d * d;
            }

            v0 = center * mask;
            v1 = wh * mask;
            v2 = imax * mask;
            v3 = imin * mask;
            v4 = cls * mask;
        }
    }

    // ---- Wave (64-lane) shuffle reduction ----
#pragma unroll
    for (int off = 32; off > 0; off >>= 1) {
        v0 += __shfl_down(v0, off);
        v1 += __shfl_down(v1, off);
        v2 += __shfl_down(v2, off);
        v3 += __shfl_down(v3, off);
        v4 += __shfl_down(v4, off);
    }

    const int wave = tid >> 6;
    const int lane = tid & 63;
    if (lane == 0) {
        red[0][wave] = v0;
        red[1][wave] = v1;
        red[2][wave] = v2;
        red[3][wave] = v3;
        red[4][wave] = v4;
    }
    __syncthreads();

    if (tid < 5) {
        float s = 0.f;
#pragma unroll
        for (int w = 0; w < TPB / 64; ++w) s += red[tid][w];
        atomicAdd(&out[tid], s);
    }
}

extern "C" void kernel_launch(void* const* d_in, const int* in_sizes, int n_in,
                              void* d_out, int out_size, void* d_ws, size_t ws_size,
                              hipStream_t stream) {
    const float* pred = (const float*)d_in[0];
    const float* lab  = (const float*)d_in[1];
    float* out = (float*)d_out;

    const int n_cells = in_sizes[0] / NCH;   // 16384*7*7 = 802816 (divisible by 256)
    const int grid = (n_cells + CPB - 1) / CPB;

    hipMemsetAsync(d_out, 0, out_size * sizeof(float), stream);
    hipLaunchKernelGGL(yolo_loss, dim3(grid), dim3(TPB), 0, stream,
                       pred, lab, out, n_cells);
}

// Round 3
// 208.490 us; speedup vs baseline: 1.0635x; 1.0635x over previous
//
#include <hip/hip_runtime.h>

#define NCH 30      // channels per cell
#define CPB 256     // cells per block
#define TPB 256     // threads per block

__device__ __forceinline__ float iou_f(float x1, float y1, float w1, float h1,
                                       float x2, float y2, float w2, float h2) {
    float l1 = x1 - 0.5f * w1, r1 = x1 + 0.5f * w1;
    float t1 = y1 - 0.5f * h1, b1 = y1 + 0.5f * h1;
    float l2 = x2 - 0.5f * w2, r2 = x2 + 0.5f * w2;
    float t2 = y2 - 0.5f * h2, b2 = y2 + 0.5f * h2;
    float in_h = fminf(b1, b2) - fmaxf(t1, t2);
    float in_w = fminf(r1, r2) - fmaxf(l1, l2);
    float inter = (in_h < 0.f || in_w < 0.f) ? 0.f : in_h * in_w;
    float a1 = (b1 - t1) * (r1 - l1);
    float a2 = (b2 - t2) * (r2 - l2);
    return inter / (a1 + a2 - inter);
}

// Kernel 1: per-block partial sums -> d_ws (NO atomics; 3136x5 plain stores).
__global__ __launch_bounds__(TPB) void yolo_partial(const float* __restrict__ pred,
                                                    const float* __restrict__ lab,
                                                    float* __restrict__ partial) {
    __shared__ float s_p[CPB * NCH];
    __shared__ float s_l[CPB * NCH];
    __shared__ float red[5][TPB / 64];

    const int tid = threadIdx.x;
    const size_t base_vec = (size_t)blockIdx.x * (CPB * NCH / 4);

    // ---- Stage global -> LDS, coalesced float4 (n_cells % CPB == 0, no guards) ----
    const float4* gp = (const float4*)pred + base_vec;
    const float4* gl = (const float4*)lab + base_vec;
    float4* sp = (float4*)s_p;
    float4* sl = (float4*)s_l;
#pragma unroll
    for (int i = 0; i < CPB * NCH / 4; i += TPB) {   // 1920 float4 per array
        sp[i + tid] = gp[i + tid];
        sl[i + tid] = gl[i + tid];
    }
    __syncthreads();

    // ---- Per-cell compute ----
    const float* cp = s_p + tid * NCH;
    const float* cl = s_l + tid * NCH;
    float mask = cl[0];
    float gx = cl[1], gy = cl[2], gw = cl[3], gh = cl[4];

    float i1 = iou_f(cp[1], cp[2], cp[3], cp[4], gx, gy, gw, gh);
    float i2 = iou_f(cp[6], cp[7], cp[8], cp[9], gx, gy, gw, gh);
    bool best = (i1 >= i2);
    float sx = best ? cp[1] : cp[6];
    float sy = best ? cp[2] : cp[7];
    float sw = best ? cp[3] : cp[8];
    float sh = best ? cp[4] : cp[9];
    float imax = best ? i1 : i2;
    float imin = best ? i2 : i1;

    float center = 5.f * ((sx - gx) * (sx - gx) + (sy - gy) * (sy - gy));
    float dw = sqrtf(sw) - sqrtf(gw);
    float dh = sqrtf(sh) - sqrtf(gh);
    float wh = 5.f * (dw * dw + dh * dh);

    float cls = 0.f;
#pragma unroll
    for (int c = 10; c < 30; ++c) {
        float d = cp[c] - cl[c];
        cls += d * d;
    }

    float v0 = center * mask;
    float v1 = wh * mask;
    float v2 = imax * mask;
    float v3 = imin * mask;
    float v4 = cls * mask;

    // ---- Wave (64-lane) shuffle reduction ----
#pragma unroll
    for (int off = 32; off > 0; off >>= 1) {
        v0 += __shfl_down(v0, off);
        v1 += __shfl_down(v1, off);
        v2 += __shfl_down(v2, off);
        v3 += __shfl_down(v3, off);
        v4 += __shfl_down(v4, off);
    }

    const int wave = tid >> 6;
    const int lane = tid & 63;
    if (lane == 0) {
        red[0][wave] = v0;
        red[1][wave] = v1;
        red[2][wave] = v2;
        red[3][wave] = v3;
        red[4][wave] = v4;
    }
    __syncthreads();

    if (tid < 5) {
        float s = 0.f;
#pragma unroll
        for (int w = 0; w < TPB / 64; ++w) s += red[tid][w];
        partial[(size_t)blockIdx.x * 5 + tid] = s;   // plain store, no contention
    }
}

// Kernel 2: reduce n_blocks x 5 partials -> out[0..4]. One block.
__global__ __launch_bounds__(256) void final_reduce(const float* __restrict__ partial,
                                                    float* __restrict__ out,
                                                    int n_blocks) {
    __shared__ float red[5][4];
    const int tid = threadIdx.x;
    float v0 = 0.f, v1 = 0.f, v2 = 0.f, v3 = 0.f, v4 = 0.f;
    for (int b = tid; b < n_blocks; b += 256) {
        const float* p = partial + (size_t)b * 5;
        v0 += p[0]; v1 += p[1]; v2 += p[2]; v3 += p[3]; v4 += p[4];
    }
#pragma unroll
    for (int off = 32; off > 0; off >>= 1) {
        v0 += __shfl_down(v0, off);
        v1 += __shfl_down(v1, off);
        v2 += __shfl_down(v2, off);
        v3 += __shfl_down(v3, off);
        v4 += __shfl_down(v4, off);
    }
    const int wave = tid >> 6;
    const int lane = tid & 63;
    if (lane == 0) {
        red[0][wave] = v0;
        red[1][wave] = v1;
        red[2][wave] = v2;
        red[3][wave] = v3;
        red[4][wave] = v4;
    }
    __syncthreads();
    if (tid < 5) {
        float s = 0.f;
#pragma unroll
        for (int w = 0; w < 4; ++w) s += red[tid][w];
        out[tid] = s;
    }
}

extern "C" void kernel_launch(void* const* d_in, const int* in_sizes, int n_in,
                              void* d_out, int out_size, void* d_ws, size_t ws_size,
                              hipStream_t stream) {
    const float* pred = (const float*)d_in[0];
    const float* lab  = (const float*)d_in[1];
    float* out = (float*)d_out;
    float* partial = (float*)d_ws;                 // needs 3136*5*4 = 62,720 B

    const int n_cells = in_sizes[0] / NCH;         // 802816, divisible by 256
    const int grid = n_cells / CPB;                // 3136

    hipLaunchKernelGGL(yolo_partial, dim3(grid), dim3(TPB), 0, stream,
                       pred, lab, partial);
    hipLaunchKernelGGL(final_reduce, dim3(1), dim3(256), 0, stream,
                       partial, out, grid);
}

// Round 4
// 203.152 us; speedup vs baseline: 1.0914x; 1.0263x over previous
//
#include <hip/hip_runtime.h>

#define NCH 30      // channels per cell (cell = 120 B, 8 B-aligned)
#define TPB 256

__device__ __forceinline__ float iou_f(float x1, float y1, float w1, float h1,
                                       float x2, float y2, float w2, float h2) {
    float l1 = x1 - 0.5f * w1, r1 = x1 + 0.5f * w1;
    float t1 = y1 - 0.5f * h1, b1 = y1 + 0.5f * h1;
    float l2 = x2 - 0.5f * w2, r2 = x2 + 0.5f * w2;
    float t2 = y2 - 0.5f * h2, b2 = y2 + 0.5f * h2;
    float in_h = fminf(b1, b2) - fmaxf(t1, t2);
    float in_w = fminf(r1, r2) - fmaxf(l1, l2);
    float inter = (in_h < 0.f || in_w < 0.f) ? 0.f : in_h * in_w;
    float a1 = (b1 - t1) * (r1 - l1);
    float a2 = (b2 - t2) * (r2 - l2);
    return inter / (a1 + a2 - inter);
}

// One thread per cell. No LDS staging, no block-wide load barrier.
// mask ∈ {0,1}; for mask==0 cells only 8 B of labels is ever touched.
__global__ __launch_bounds__(TPB) void yolo_partial(const float* __restrict__ pred,
                                                    const float* __restrict__ lab,
                                                    float* __restrict__ partial,
                                                    int n_cells) {
    __shared__ float red[5][TPB / 64];
    const int tid = threadIdx.x;
    const size_t c = (size_t)blockIdx.x * TPB + tid;

    float v0 = 0.f, v1 = 0.f, v2 = 0.f, v3 = 0.f, v4 = 0.f;

    if (c < (size_t)n_cells) {
        const float* lp = lab + c * NCH;
        const float2 l01 = *(const float2*)(lp);        // ch0 (mask), ch1 (gx)
        const float mask = l01.x;

        if (mask != 0.f) {
            const float* pp = pred + c * NCH;
            const float2 l23 = *(const float2*)(lp + 2); // gy, gw
            const float2 l45 = *(const float2*)(lp + 4); // gh, -
            const float gx = l01.y, gy = l23.x, gw = l23.y, gh = l45.x;

            const float2 p01 = *(const float2*)(pp);     // -, b1x
            const float2 p23 = *(const float2*)(pp + 2); // b1y, b1w
            const float2 p45 = *(const float2*)(pp + 4); // b1h, -
            const float2 p67 = *(const float2*)(pp + 6); // b2x, b2y
            const float2 p89 = *(const float2*)(pp + 8); // b2w, b2h

            const float i1 = iou_f(p01.y, p23.x, p23.y, p45.x, gx, gy, gw, gh);
            const float i2 = iou_f(p67.x, p67.y, p89.x, p89.y, gx, gy, gw, gh);
            const bool best = (i1 >= i2);
            const float sx = best ? p01.y : p67.x;
            const float sy = best ? p23.x : p67.y;
            const float sw = best ? p23.y : p89.x;
            const float sh = best ? p45.x : p89.y;
            const float imax = best ? i1 : i2;
            const float imin = best ? i2 : i1;

            const float center = 5.f * ((sx - gx) * (sx - gx) + (sy - gy) * (sy - gy));
            const float dw = sqrtf(sw) - sqrtf(gw);
            const float dh = sqrtf(sh) - sqrtf(gh);
            const float wh = 5.f * (dw * dw + dh * dh);

            float cls = 0.f;
#pragma unroll
            for (int k = 0; k < 10; ++k) {               // channels 10..29
                const float2 pd = *(const float2*)(pp + 10 + 2 * k);
                const float2 ld = *(const float2*)(lp + 10 + 2 * k);
                const float dx = pd.x - ld.x;
                const float dy = pd.y - ld.y;
                cls += dx * dx + dy * dy;
            }

            v0 = center * mask;
            v1 = wh * mask;
            v2 = imax * mask;
            v3 = imin * mask;
            v4 = cls * mask;
        }
    }

    // ---- Wave (64-lane) shuffle reduction ----
#pragma unroll
    for (int off = 32; off > 0; off >>= 1) {
        v0 += __shfl_down(v0, off);
        v1 += __shfl_down(v1, off);
        v2 += __shfl_down(v2, off);
        v3 += __shfl_down(v3, off);
        v4 += __shfl_down(v4, off);
    }

    const int wave = tid >> 6;
    const int lane = tid & 63;
    if (lane == 0) {
        red[0][wave] = v0;
        red[1][wave] = v1;
        red[2][wave] = v2;
        red[3][wave] = v3;
        red[4][wave] = v4;
    }
    __syncthreads();

    if (tid < 5) {
        float s = 0.f;
#pragma unroll
        for (int w = 0; w < TPB / 64; ++w) s += red[tid][w];
        partial[(size_t)blockIdx.x * 5 + tid] = s;   // plain store, no contention
    }
}

// Reduce n_blocks x 5 partials -> out[0..4]. One block.
__global__ __launch_bounds__(256) void final_reduce(const float* __restrict__ partial,
                                                    float* __restrict__ out,
                                                    int n_blocks) {
    __shared__ float red[5][4];
    const int tid = threadIdx.x;
    float v0 = 0.f, v1 = 0.f, v2 = 0.f, v3 = 0.f, v4 = 0.f;
    for (int b = tid; b < n_blocks; b += 256) {
        const float* p = partial + (size_t)b * 5;
        v0 += p[0]; v1 += p[1]; v2 += p[2]; v3 += p[3]; v4 += p[4];
    }
#pragma unroll
    for (int off = 32; off > 0; off >>= 1) {
        v0 += __shfl_down(v0, off);
        v1 += __shfl_down(v1, off);
        v2 += __shfl_down(v2, off);
        v3 += __shfl_down(v3, off);
        v4 += __shfl_down(v4, off);
    }
    const int wave = tid >> 6;
    const int lane = tid & 63;
    if (lane == 0) {
        red[0][wave] = v0;
        red[1][wave] = v1;
        red[2][wave] = v2;
        red[3][wave] = v3;
        red[4][wave] = v4;
    }
    __syncthreads();
    if (tid < 5) {
        float s = 0.f;
#pragma unroll
        for (int w = 0; w < 4; ++w) s += red[tid][w];
        out[tid] = s;
    }
}

extern "C" void kernel_launch(void* const* d_in, const int* in_sizes, int n_in,
                              void* d_out, int out_size, void* d_ws, size_t ws_size,
                              hipStream_t stream) {
    const float* pred = (const float*)d_in[0];
    const float* lab  = (const float*)d_in[1];
    float* out = (float*)d_out;
    float* partial = (float*)d_ws;                 // 3136*5*4 = 62,720 B

    const int n_cells = in_sizes[0] / NCH;         // 802816
    const int grid = (n_cells + TPB - 1) / TPB;    // 3136

    hipLaunchKernelGGL(yolo_partial, dim3(grid), dim3(TPB), 0, stream,
                       pred, lab, partial, n_cells);
    hipLaunchKernelGGL(final_reduce, dim3(1), dim3(256), 0, stream,
                       partial, out, grid);
}